// Round 2
// baseline (584.994 us; speedup 1.0000x reference)
//
#include <hip/hip_runtime.h>

typedef __bf16 bf16_t;
typedef __bf16 bf16x8 __attribute__((ext_vector_type(8)));
typedef __bf16 bf16x4 __attribute__((ext_vector_type(4)));
typedef float  f32x4  __attribute__((ext_vector_type(4)));

#define MFMA16(a,b,c) __builtin_amdgcn_mfma_f32_16x16x32_bf16((a),(b),(c),0,0,0)

#define NB 4          // batch
#define LL 4096       // seq
#define CC 1024       // channels
#define HH 8          // heads
#define RR 512        // low-rank seq
#define GRID 768      // 3 blocks/CU x 256 CUs -- co-resident by construction

// ---------- grid-wide barrier: monotonic count, device-scope atomics (cross-XCD safe) ----
__device__ __forceinline__ void gsync(unsigned* cnt, unsigned target) {
  __syncthreads();
  if (threadIdx.x == 0) {
    __threadfence();                          // release: WB this XCD's L2
    atomicAdd(cnt, 1u);
    while (atomicAdd(cnt, 0u) < target) __builtin_amdgcn_s_sleep(8);
    __threadfence();                          // acquire: INV L1/L2
  }
  __syncthreads();
}

// ---------------- async 16B global->LDS staging (m97 pattern: unpadded stride-32 rows) ----
template <int CH>
__device__ __forceinline__ void stage_async(const bf16_t* __restrict__ g, bf16_t* __restrict__ s, int t) {
#pragma unroll
  for (int j = 0; j < CH; ++j) {
    int c = t + j * 256;                     // 16B chunk id; lane-contiguous per wave
    const bf16_t* ga = g + (c >> 2) * 1024 + (c & 3) * 8;
    bf16_t* la = s + c * 8;
    __builtin_amdgcn_global_load_lds((const __attribute__((address_space(1))) void*)ga,
                                     (__attribute__((address_space(3))) void*)la, 16, 0, 0);
  }
}

// ---------------- GEMM core: C[BM,BN] tile of A[M,1024] * W[N,1024]^T ----------------
// 3-buffer / 2-deep prefetch, counted vmcnt, one s_barrier per K-step.
// MODE 0 (BN=128): z=0/1 -> rmsnorm+rope -> q1/q2 | k1/k2 ; z=2 -> Vt transposed bf16
// MODE 1: Wo + silu -> f32 lowrank
template <int MODE, int BM, int BN>
__device__ __forceinline__ void gemm_core(const bf16_t* __restrict__ A, const bf16_t* __restrict__ W,
                                          const float* __restrict__ qw, const float* __restrict__ kw,
                                          bf16_t* __restrict__ q1, bf16_t* __restrict__ q2,
                                          bf16_t* __restrict__ k1, bf16_t* __restrict__ k2,
                                          bf16_t* __restrict__ vt, float* __restrict__ outF,
                                          bf16_t* sA, bf16_t* sB, int m0, int n0, int z, int t) {
  int lane = t & 63, w = t >> 6;
  int wr = w >> 1, wc = w & 1;
  int lr = lane & 15, quad = lane >> 4;
  constexpr int NI = BM / 32, NJ = BN / 32;
  f32x4 acc[NI][NJ] = {};
  const bf16_t* Ab = A + (size_t)m0 * 1024;
  const bf16_t* Wb = W + (size_t)n0 * 1024;

  // prologue: stage K-steps 0 and 1
  stage_async<BM / 64>(Ab, sA, t);
  stage_async<BN / 64>(Wb, sB, t);
  stage_async<BM / 64>(Ab + 32, sA + BM * 32, t);
  stage_async<BN / 64>(Wb + 32, sB + BN * 32, t);

  int cur = 0, stg = 2;
#pragma unroll 1
  for (int it = 0; it < 32; ++it) {
    if (it < 31) {
      constexpr int L = BM / 64 + BN / 64;   // loads per thread per stage
      if constexpr (L == 2) asm volatile("s_waitcnt vmcnt(2) lgkmcnt(0)" ::: "memory");
      else if constexpr (L == 3) asm volatile("s_waitcnt vmcnt(3) lgkmcnt(0)" ::: "memory");
      else asm volatile("s_waitcnt vmcnt(4) lgkmcnt(0)" ::: "memory");
    } else {
      asm volatile("s_waitcnt vmcnt(0) lgkmcnt(0)" ::: "memory");
    }
    __builtin_amdgcn_s_barrier();             // buf[it] staged everywhere; buf[it-1] reads done
    if (it < 30) {
      stage_async<BM / 64>(Ab + (it + 2) * 32, sA + stg * (BM * 32), t);
      stage_async<BN / 64>(Wb + (it + 2) * 32, sB + stg * (BN * 32), t);
    }
    const bf16_t* cA = sA + cur * (BM * 32);
    const bf16_t* cB = sB + cur * (BN * 32);
    bf16x8 af[NI], bfr[NJ];
#pragma unroll
    for (int i = 0; i < NI; ++i) af[i] = *(const bf16x8*)&cA[(wr * (BM / 2) + i * 16 + lr) * 32 + quad * 8];
#pragma unroll
    for (int j = 0; j < NJ; ++j) bfr[j] = *(const bf16x8*)&cB[(wc * (BN / 2) + j * 16 + lr) * 32 + quad * 8];
#pragma unroll
    for (int i = 0; i < NI; ++i)
#pragma unroll
      for (int j = 0; j < NJ; ++j)
        acc[i][j] = MFMA16(af[i], bfr[j], acc[i][j]);
    cur = (cur == 2) ? 0 : cur + 1;
    stg = (stg == 2) ? 0 : stg + 1;
  }

  if constexpr (MODE == 1) {
#pragma unroll
    for (int i = 0; i < NI; ++i)
#pragma unroll
      for (int j = 0; j < NJ; ++j) {
        int row0 = m0 + wr * (BM / 2) + i * 16 + quad * 4;
        int col  = n0 + wc * (BN / 2) + j * 16 + lr;
#pragma unroll
        for (int rg = 0; rg < 4; ++rg) {
          float v = acc[i][j][rg];
          outF[(size_t)(row0 + rg) * 1024 + col] = v / (1.f + __expf(-v));
        }
      }
    return;
  } else {
    if (z == 2) {
#pragma unroll
      for (int i = 0; i < NI; ++i)
#pragma unroll
        for (int j = 0; j < NJ; ++j) {
          int row0 = m0 + wr * (BM / 2) + i * 16 + quad * 4;
          int col  = n0 + wc * (BN / 2) + j * 16 + lr;
          int b = row0 >> 9, ii = row0 & 511;
          int h = col >> 7, nn = col & 127;
          bf16x4 pk;
#pragma unroll
          for (int rg = 0; rg < 4; ++rg) pk[rg] = (bf16_t)acc[i][j][rg];
          *(bf16x4*)&vt[(size_t)((b * HH + h) * 128 + nn) * 512 + ii] = pk;
        }
      return;
    }
    // z<2: fused rmsnorm(64) + rope (pos = head idx) epilogue; wave col span = one (h,slot) group
    const float* nw = z ? kw : qw;
    int colbase = n0 + wc * (BN / 2);
    int h = colbase >> 7;
    int slot = (colbase >> 6) & 1;
    bf16_t* dst = (z == 0) ? (slot ? q2 : q1) : (slot ? k2 : k1);
    float qs = (z == 0) ? 0.125f : 1.0f;      // fold attn scale into q
    float w0 = nw[lr], w1 = nw[16 + lr], w2 = nw[32 + lr], w3 = nw[48 + lr];
    const float nlog = -13.287712379549449f / 32.f;   // -log2(10000)/32
    float f0 = exp2f((float)lr * nlog);
    float f1 = exp2f((float)(16 + lr) * nlog);
    float sn0, cs0, sn1, cs1;
    __sincosf((float)h * f0, &sn0, &cs0);
    __sincosf((float)h * f1, &sn1, &cs1);
#pragma unroll
    for (int i = 0; i < NI; ++i) {
#pragma unroll
      for (int rg = 0; rg < 4; ++rg) {
        float v0 = acc[i][0][rg], v1 = acc[i][1][rg], v2 = acc[i][2][rg], v3 = acc[i][3][rg];
        float ss = v0 * v0 + v1 * v1 + v2 * v2 + v3 * v3;
#pragma unroll
        for (int m = 1; m <= 8; m <<= 1) ss += __shfl_xor(ss, m);   // over 16 lr lanes
        float rinv = qs / sqrtf(ss * (1.f / 64.f) + 1e-6f);
        float n0v = v0 * rinv * w0, n1v = v1 * rinv * w1, n2v = v2 * rinv * w2, n3v = v3 * rinv * w3;
        float o0 = n0v * cs0 - n2v * sn0;
        float o1 = n1v * cs1 - n3v * sn1;
        float o2 = n0v * sn0 + n2v * cs0;
        float o3 = n1v * sn1 + n3v * cs1;
        int row = m0 + wr * (BM / 2) + i * 16 + quad * 4 + rg;
        int b = row >> 9, seq = row & 511;
        size_t base = ((size_t)((b * HH + h) * RR + seq)) * 64;
        dst[base + lr]      = (bf16_t)o0;
        dst[base + 16 + lr] = (bf16_t)o1;
        dst[base + 32 + lr] = (bf16_t)o2;
        dst[base + 48 + lr] = (bf16_t)o3;
      }
    }
  }
}

// =========================== the fused persistent kernel ===========================
__global__ __launch_bounds__(256, 3) void mega(
    const float* __restrict__ x,
    const float* __restrict__ Wq, const float* __restrict__ Wk,
    const float* __restrict__ Wv, const float* __restrict__ Wo,
    const float* __restrict__ qw, const float* __restrict__ kw,
    const float* __restrict__ hw,
    const float* __restrict__ lq1, const float* __restrict__ lk1,
    const float* __restrict__ lq2, const float* __restrict__ lk2,
    bf16_t* __restrict__ wbf, bf16_t* __restrict__ xd, bf16_t* __restrict__ vt,
    bf16_t* __restrict__ q1, bf16_t* __restrict__ q2,
    bf16_t* __restrict__ k1, bf16_t* __restrict__ k2,
    bf16_t* __restrict__ anorm, float* __restrict__ lowrank,
    float* __restrict__ out, unsigned* cnt) {
  __shared__ __align__(16) char smem[36864];   // gemm: sA 12288 + sB 24576 | attn: 17920
  bf16_t* sA = (bf16_t*)smem;
  bf16_t* sB = (bf16_t*)(smem + 12288);
  int t = threadIdx.x;
  int bid = blockIdx.x;
  int lane = t & 63, wv = t >> 6;
  int lr = lane & 15, quad = lane >> 4;

  // ---------------- P0: weight convert (4096 tasks) + downsample (2048 tasks) ----------
  for (int task = bid; task < 6144; task += GRID) {
    if (task < 4096) {
      int y = task >> 10;
      const float* src = (y == 0) ? Wq : (y == 1) ? Wk : (y == 2) ? Wv : Wo;
      int idx = (task & 1023) * 256 + t;
      f32x4 v = *(const f32x4*)&src[(size_t)idx * 4];
      bf16x4 o;
#pragma unroll
      for (int j = 0; j < 4; ++j) o[j] = (bf16_t)v[j];
      *(bf16x4*)&wbf[(size_t)y * 1048576 + (size_t)idx * 4] = o;
    } else {
      int idx = (task - 4096) * 256 + t;
      int c4  = idx & 255;
      int row = idx >> 8;                            // b*512 + i
      int b = row >> 9, i = row & 511;
      const float* p0 = x + (size_t)(b * LL + 8 * i + 3) * CC + c4 * 4;  // coords=8i+3.5
      f32x4 a = *(const f32x4*)p0;
      f32x4 bb = *(const f32x4*)(p0 + CC);
      bf16x4 o;
#pragma unroll
      for (int j = 0; j < 4; ++j) o[j] = (bf16_t)(0.5f * (a[j] + bb[j]));
      *(bf16x4*)&xd[(size_t)row * CC + c4 * 4] = o;
    }
  }
  gsync(cnt, GRID);

  // ---------------- P1: QKV gemm, BM=64 -> exactly 768 tiles ----------------
  {
    int z = bid >> 8, rem = bid & 255;
    int n0 = (rem & 7) * 128, m0 = (rem >> 3) * 64;
    gemm_core<0, 64, 128>(xd, wbf + (size_t)z * (1u << 20), qw, kw,
                          q1, q2, k1, k2, vt, nullptr, sA, sB, m0, n0, z, t);
  }
  gsync(cnt, 2 * GRID);

  // ---------------- P2: differential attention (1024 tasks, grid-stride) --------------
  {
    bf16_t* P   = (bf16_t*)smem;                 // [16][520]
    float* Sf   = (float*)(smem + 16640);
    float* Sm1 = Sf, *Sl1 = Sf + 64, *Sm2 = Sf + 128, *Sl2 = Sf + 192, *Sq = Sf + 256;

    float t1 = lq1[lane] * lk1[lane];
    float t2 = lq2[lane] * lk2[lane];
#pragma unroll
    for (int m = 1; m <= 32; m <<= 1) { t1 += __shfl_xor(t1, m); t2 += __shfl_xor(t2, m); }
    float lam = expf(t1) - expf(t2) + 0.8f;

    for (int task = bid; task < 1024; task += GRID) {
      int qt = task & 31, bh = task >> 5;
      int b = bh >> 3, h = bh & 7;
      const bf16_t* q1b = q1 + (size_t)(bh * RR + qt * 16) * 64;
      const bf16_t* q2b = q2 + (size_t)(bh * RR + qt * 16) * 64;
      const bf16_t* k1b = k1 + (size_t)bh * RR * 64;
      const bf16_t* k2b = k2 + (size_t)bh * RR * 64;
      const bf16_t* vtb = vt + (size_t)bh * 128 * 512;

      bf16x8 a1[2], a2[2];
#pragma unroll
      for (int kk = 0; kk < 2; ++kk) {
        a1[kk] = *(const bf16x8*)&q1b[lr * 64 + kk * 32 + quad * 8];
        a2[kk] = *(const bf16x8*)&q2b[lr * 64 + kk * 32 + quad * 8];
      }
      f32x4 s1[8], s2[8];
#pragma unroll
      for (int kt = 0; kt < 8; ++kt) {
        const bf16_t* kr = k1b + (size_t)((wv * 8 + kt) * 16 + lr) * 64 + quad * 8;
        f32x4 a = {};
        a = MFMA16(a1[0], *(const bf16x8*)kr, a);
        a = MFMA16(a1[1], *(const bf16x8*)(kr + 32), a);
        s1[kt] = a;
      }
#pragma unroll
      for (int kt = 0; kt < 8; ++kt) {
        const bf16_t* kr = k2b + (size_t)((wv * 8 + kt) * 16 + lr) * 64 + quad * 8;
        f32x4 a = {};
        a = MFMA16(a2[0], *(const bf16x8*)kr, a);
        a = MFMA16(a2[1], *(const bf16x8*)(kr + 32), a);
        s2[kt] = a;
      }
      float m1[4] = {-3e38f, -3e38f, -3e38f, -3e38f}, m2[4] = {-3e38f, -3e38f, -3e38f, -3e38f};
#pragma unroll
      for (int kt = 0; kt < 8; ++kt)
#pragma unroll
        for (int rg = 0; rg < 4; ++rg) { m1[rg] = fmaxf(m1[rg], s1[kt][rg]); m2[rg] = fmaxf(m2[rg], s2[kt][rg]); }
#pragma unroll
      for (int m = 1; m <= 8; m <<= 1)
#pragma unroll
        for (int rg = 0; rg < 4; ++rg) { m1[rg] = fmaxf(m1[rg], __shfl_xor(m1[rg], m)); m2[rg] = fmaxf(m2[rg], __shfl_xor(m2[rg], m)); }
      float l1[4] = {}, l2[4] = {};
#pragma unroll
      for (int kt = 0; kt < 8; ++kt)
#pragma unroll
        for (int rg = 0; rg < 4; ++rg) {
          float e1 = __expf(s1[kt][rg] - m1[rg]); s1[kt][rg] = e1; l1[rg] += e1;
          float e2 = __expf(s2[kt][rg] - m2[rg]); s2[kt][rg] = e2; l2[rg] += e2;
        }
#pragma unroll
      for (int m = 1; m <= 8; m <<= 1)
#pragma unroll
        for (int rg = 0; rg < 4; ++rg) { l1[rg] += __shfl_xor(l1[rg], m); l2[rg] += __shfl_xor(l2[rg], m); }
      if (lr == 0) {
#pragma unroll
        for (int rg = 0; rg < 4; ++rg) {
          int r = quad * 4 + rg;
          Sm1[wv * 16 + r] = m1[rg]; Sl1[wv * 16 + r] = l1[rg];
          Sm2[wv * 16 + r] = m2[rg]; Sl2[wv * 16 + r] = l2[rg];
        }
      }
      __syncthreads();
      float sc1[4], sc2[4];
#pragma unroll
      for (int rg = 0; rg < 4; ++rg) {
        int r = quad * 4 + rg;
        float gm1 = fmaxf(fmaxf(Sm1[r], Sm1[16 + r]), fmaxf(Sm1[32 + r], Sm1[48 + r]));
        float L1 = Sl1[r] * __expf(Sm1[r] - gm1) + Sl1[16 + r] * __expf(Sm1[16 + r] - gm1)
                 + Sl1[32 + r] * __expf(Sm1[32 + r] - gm1) + Sl1[48 + r] * __expf(Sm1[48 + r] - gm1);
        sc1[rg] = __expf(m1[rg] - gm1) / L1;
        float gm2 = fmaxf(fmaxf(Sm2[r], Sm2[16 + r]), fmaxf(Sm2[32 + r], Sm2[48 + r]));
        float L2 = Sl2[r] * __expf(Sm2[r] - gm2) + Sl2[16 + r] * __expf(Sm2[16 + r] - gm2)
                 + Sl2[32 + r] * __expf(Sm2[32 + r] - gm2) + Sl2[48 + r] * __expf(Sm2[48 + r] - gm2);
        sc2[rg] = lam * __expf(m2[rg] - gm2) / L2;
      }
#pragma unroll
      for (int kt = 0; kt < 8; ++kt)
#pragma unroll
        for (int rg = 0; rg < 4; ++rg) {
          float v = s1[kt][rg] * sc1[rg] - s2[kt][rg] * sc2[rg];
          P[(quad * 4 + rg) * 520 + (wv * 8 + kt) * 16 + lr] = (bf16_t)v;
        }
      __syncthreads();
      f32x4 accO[2] = {};
#pragma unroll
      for (int ks = 0; ks < 16; ++ks) {
        bf16x8 pf = *(bf16x8*)&P[lr * 520 + ks * 32 + quad * 8];
#pragma unroll
        for (int j = 0; j < 2; ++j) {
          int nt = wv * 2 + j;
          bf16x8 vf = *(const bf16x8*)&vtb[(size_t)(nt * 16 + lr) * 512 + ks * 32 + quad * 8];
          accO[j] = MFMA16(pf, vf, accO[j]);
        }
      }
      float ssr[4] = {};
#pragma unroll
      for (int j = 0; j < 2; ++j)
#pragma unroll
        for (int rg = 0; rg < 4; ++rg) ssr[rg] += accO[j][rg] * accO[j][rg];
#pragma unroll
      for (int m = 1; m <= 8; m <<= 1)
#pragma unroll
        for (int rg = 0; rg < 4; ++rg) ssr[rg] += __shfl_xor(ssr[rg], m);
      if (lr == 0) {
#pragma unroll
        for (int rg = 0; rg < 4; ++rg) Sq[wv * 16 + quad * 4 + rg] = ssr[rg];
      }
      __syncthreads();
#pragma unroll
      for (int j = 0; j < 2; ++j) {
        int nt = wv * 2 + j;
        float wcol = hw[nt * 16 + lr];
#pragma unroll
        for (int rg = 0; rg < 4; ++rg) {
          int r = quad * 4 + rg;
          float tot = Sq[r] + Sq[16 + r] + Sq[32 + r] + Sq[48 + r];
          float rinv = 0.2f / sqrtf(tot * (1.f / 128.f) + 1e-6f);
          int i = qt * 16 + r;
          anorm[(size_t)(b * RR + i) * 1024 + h * 128 + nt * 16 + lr] = (bf16_t)(accO[j][rg] * rinv * wcol);
        }
      }
    }
  }
  gsync(cnt, 3 * GRID);

  // ---------------- P3: output gemm + silu, BM=64 BN=64 -> 512 tiles ----------------
  if (bid < 512) {
    int n0 = (bid & 15) * 64, m0 = (bid >> 4) * 64;
    gemm_core<1, 64, 64>(anorm, wbf + (size_t)3 * (1u << 20), qw, kw,
                         nullptr, nullptr, nullptr, nullptr, nullptr, lowrank,
                         sA, sB, m0, n0, 3, t);
  }
  gsync(cnt, 4 * GRID);

  // ---------------- P4: upsample lowrank -> full output (16384 row-tasks) -------------
  for (int task = bid; task < 16384; task += GRID) {
    int j = task & 4095, b = task >> 12;
    int c = t * 4;
    float coord = 0.125f * (float)j - 0.4375f;
    coord = fminf(fmaxf(coord, 0.f), 511.f);
    int lo = (int)floorf(coord);
    int hi = lo + 1 < 511 ? lo + 1 : 511;
    float wt = coord - (float)lo;
    f32x4 a = *(const f32x4*)&lowrank[(size_t)(b * RR + lo) * CC + c];
    f32x4 bb = *(const f32x4*)&lowrank[(size_t)(b * RR + hi) * CC + c];
    f32x4 o;
#pragma unroll
    for (int q = 0; q < 4; ++q) o[q] = a[q] * (1.f - wt) + bb[q] * wt;
    *(f32x4*)&out[(size_t)(b * LL + j) * CC + c] = o;
  }
}

extern "C" void kernel_launch(void* const* d_in, const int* in_sizes, int n_in,
                              void* d_out, int out_size, void* d_ws, size_t ws_size,
                              hipStream_t stream) {
  (void)in_sizes; (void)n_in; (void)out_size; (void)ws_size;
  const float* x   = (const float*)d_in[0];
  const float* Wq  = (const float*)d_in[1];
  const float* Wk  = (const float*)d_in[2];
  const float* Wv  = (const float*)d_in[3];
  const float* Wo  = (const float*)d_in[4];
  const float* qw  = (const float*)d_in[5];
  const float* kw  = (const float*)d_in[6];
  const float* hw  = (const float*)d_in[7];
  const float* lq1 = (const float*)d_in[8];
  const float* lk1 = (const float*)d_in[9];
  const float* lq2 = (const float*)d_in[10];
  const float* lk2 = (const float*)d_in[11];
  float* out = (float*)d_out;

  char* ws = (char*)d_ws;
  bf16_t* wbf   = (bf16_t*)(ws);                    // 8 MB: Wq,Wk,Wv,Wo bf16
  bf16_t* xd    = (bf16_t*)(ws + (8u << 20));       // 4 MB
  bf16_t* vt    = (bf16_t*)(ws + (12u << 20));      // 4 MB (B,H,128,512)
  bf16_t* q1    = (bf16_t*)(ws + (16u << 20));      // 2 MB each
  bf16_t* q2    = (bf16_t*)(ws + (18u << 20));
  bf16_t* k1    = (bf16_t*)(ws + (20u << 20));
  bf16_t* k2    = (bf16_t*)(ws + (22u << 20));
  bf16_t* anorm = (bf16_t*)(ws + (24u << 20));      // 4 MB -> 28 MB
  unsigned* cnt = (unsigned*)(ws + (28u << 20));    // grid barrier counter

  float* lowrank = out + (size_t)NB * LL * CC;      // second output region (f32)

  hipMemsetAsync(cnt, 0, 4, stream);                // capture-legal stream op
  mega<<<GRID, 256, 0, stream>>>(x, Wq, Wk, Wv, Wo, qw, kw, hw, lq1, lk1, lq2, lk2,
                                 wbf, xd, vt, q1, q2, k1, k2, anorm, lowrank, out, cnt);
}

// Round 3
// 463.256 us; speedup vs baseline: 1.2628x; 1.2628x over previous
//
#include <hip/hip_runtime.h>

typedef __bf16 bf16_t;
typedef __bf16 bf16x8 __attribute__((ext_vector_type(8)));
typedef __bf16 bf16x4 __attribute__((ext_vector_type(4)));
typedef float  f32x4  __attribute__((ext_vector_type(4)));

#define MFMA16(a,b,c) __builtin_amdgcn_mfma_f32_16x16x32_bf16((a),(b),(c),0,0,0)

#define NB 4          // batch
#define LL 4096       // seq
#define CC 1024       // channels
#define HH 8          // heads
#define RR 512        // low-rank seq
#define GRID 768      // 3 blocks/CU x 256 CUs -- co-resident by construction

// ---------- grid-wide barrier: 8-way sharded arrival counters (128B apart), ----------
// ---------- RMW only on arrival; polling is pure atomic LOADs (no RMW queue) ---------
__device__ __forceinline__ void gsync(unsigned* cnt, unsigned target) {
  __syncthreads();
  if (threadIdx.x == 0) {
    __threadfence();                                   // release
    atomicAdd(&cnt[(blockIdx.x & 7) * 32], 1u);        // sharded arrival
    for (;;) {
      unsigned s = 0;
#pragma unroll
      for (int i = 0; i < 8; ++i)
        s += __hip_atomic_load(&cnt[i * 32], __ATOMIC_RELAXED, __HIP_MEMORY_SCOPE_AGENT);
      if (s >= target) break;
      __builtin_amdgcn_s_sleep(2);
    }
    __threadfence();                                   // acquire
  }
  __syncthreads();
}

// ---------------- async 16B global->LDS staging (m97 pattern: unpadded stride-32 rows) ----
template <int CH>
__device__ __forceinline__ void stage_async(const bf16_t* __restrict__ g, bf16_t* __restrict__ s, int t) {
#pragma unroll
  for (int j = 0; j < CH; ++j) {
    int c = t + j * 256;                     // 16B chunk id; lane-contiguous per wave
    const bf16_t* ga = g + (c >> 2) * 1024 + (c & 3) * 8;
    bf16_t* la = s + c * 8;
    __builtin_amdgcn_global_load_lds((const __attribute__((address_space(1))) void*)ga,
                                     (__attribute__((address_space(3))) void*)la, 16, 0, 0);
  }
}

// ---------------- GEMM core: C[BM,BN] tile of A[M,1024] * W[N,1024]^T ----------------
// 3-buffer / 2-deep prefetch, counted vmcnt, one s_barrier per K-step.
// MODE 0 (BN=128): z=0/1 -> rmsnorm+rope -> q1/q2 | k1/k2 ; z=2 -> Vt transposed bf16
// MODE 1: Wo + silu -> f32 lowrank
template <int MODE, int BM, int BN>
__device__ __forceinline__ void gemm_core(const bf16_t* __restrict__ A, const bf16_t* __restrict__ W,
                                          const float* __restrict__ qw, const float* __restrict__ kw,
                                          bf16_t* __restrict__ q1, bf16_t* __restrict__ q2,
                                          bf16_t* __restrict__ k1, bf16_t* __restrict__ k2,
                                          bf16_t* __restrict__ vt, float* __restrict__ outF,
                                          bf16_t* sA, bf16_t* sB, int m0, int n0, int z, int t) {
  int lane = t & 63, w = t >> 6;
  int wr = w >> 1, wc = w & 1;
  int lr = lane & 15, quad = lane >> 4;
  constexpr int NI = BM / 32, NJ = BN / 32;
  f32x4 acc[NI][NJ] = {};
  const bf16_t* Ab = A + (size_t)m0 * 1024;
  const bf16_t* Wb = W + (size_t)n0 * 1024;

  // prologue: stage K-steps 0 and 1
  stage_async<BM / 64>(Ab, sA, t);
  stage_async<BN / 64>(Wb, sB, t);
  stage_async<BM / 64>(Ab + 32, sA + BM * 32, t);
  stage_async<BN / 64>(Wb + 32, sB + BN * 32, t);

  int cur = 0, stg = 2;
#pragma unroll 1
  for (int it = 0; it < 32; ++it) {
    if (it < 31) {
      constexpr int L = BM / 64 + BN / 64;   // loads per thread per stage
      if constexpr (L == 2) asm volatile("s_waitcnt vmcnt(2) lgkmcnt(0)" ::: "memory");
      else if constexpr (L == 3) asm volatile("s_waitcnt vmcnt(3) lgkmcnt(0)" ::: "memory");
      else asm volatile("s_waitcnt vmcnt(4) lgkmcnt(0)" ::: "memory");
    } else {
      asm volatile("s_waitcnt vmcnt(0) lgkmcnt(0)" ::: "memory");
    }
    __builtin_amdgcn_s_barrier();             // buf[it] staged everywhere; buf[it-1] reads done
    if (it < 30) {
      stage_async<BM / 64>(Ab + (it + 2) * 32, sA + stg * (BM * 32), t);
      stage_async<BN / 64>(Wb + (it + 2) * 32, sB + stg * (BN * 32), t);
    }
    const bf16_t* cA = sA + cur * (BM * 32);
    const bf16_t* cB = sB + cur * (BN * 32);
    bf16x8 af[NI], bfr[NJ];
#pragma unroll
    for (int i = 0; i < NI; ++i) af[i] = *(const bf16x8*)&cA[(wr * (BM / 2) + i * 16 + lr) * 32 + quad * 8];
#pragma unroll
    for (int j = 0; j < NJ; ++j) bfr[j] = *(const bf16x8*)&cB[(wc * (BN / 2) + j * 16 + lr) * 32 + quad * 8];
#pragma unroll
    for (int i = 0; i < NI; ++i)
#pragma unroll
      for (int j = 0; j < NJ; ++j)
        acc[i][j] = MFMA16(af[i], bfr[j], acc[i][j]);
    cur = (cur == 2) ? 0 : cur + 1;
    stg = (stg == 2) ? 0 : stg + 1;
  }

  if constexpr (MODE == 1) {
#pragma unroll
    for (int i = 0; i < NI; ++i)
#pragma unroll
      for (int j = 0; j < NJ; ++j) {
        int row0 = m0 + wr * (BM / 2) + i * 16 + quad * 4;
        int col  = n0 + wc * (BN / 2) + j * 16 + lr;
#pragma unroll
        for (int rg = 0; rg < 4; ++rg) {
          float v = acc[i][j][rg];
          outF[(size_t)(row0 + rg) * 1024 + col] = v / (1.f + __expf(-v));
        }
      }
    return;
  } else {
    if (z == 2) {
#pragma unroll
      for (int i = 0; i < NI; ++i)
#pragma unroll
        for (int j = 0; j < NJ; ++j) {
          int row0 = m0 + wr * (BM / 2) + i * 16 + quad * 4;
          int col  = n0 + wc * (BN / 2) + j * 16 + lr;
          int b = row0 >> 9, ii = row0 & 511;
          int h = col >> 7, nn = col & 127;
          bf16x4 pk;
#pragma unroll
          for (int rg = 0; rg < 4; ++rg) pk[rg] = (bf16_t)acc[i][j][rg];
          *(bf16x4*)&vt[(size_t)((b * HH + h) * 128 + nn) * 512 + ii] = pk;
        }
      return;
    }
    // z<2: fused rmsnorm(64) + rope (pos = head idx) epilogue; wave col span = one (h,slot) group
    const float* nw = z ? kw : qw;
    int colbase = n0 + wc * (BN / 2);
    int h = colbase >> 7;
    int slot = (colbase >> 6) & 1;
    bf16_t* dst = (z == 0) ? (slot ? q2 : q1) : (slot ? k2 : k1);
    float qs = (z == 0) ? 0.125f : 1.0f;      // fold attn scale into q
    float w0 = nw[lr], w1 = nw[16 + lr], w2 = nw[32 + lr], w3 = nw[48 + lr];
    const float nlog = -13.287712379549449f / 32.f;   // -log2(10000)/32
    float f0 = exp2f((float)lr * nlog);
    float f1 = exp2f((float)(16 + lr) * nlog);
    float sn0, cs0, sn1, cs1;
    __sincosf((float)h * f0, &sn0, &cs0);
    __sincosf((float)h * f1, &sn1, &cs1);
#pragma unroll
    for (int i = 0; i < NI; ++i) {
#pragma unroll
      for (int rg = 0; rg < 4; ++rg) {
        float v0 = acc[i][0][rg], v1 = acc[i][1][rg], v2 = acc[i][2][rg], v3 = acc[i][3][rg];
        float ss = v0 * v0 + v1 * v1 + v2 * v2 + v3 * v3;
#pragma unroll
        for (int m = 1; m <= 8; m <<= 1) ss += __shfl_xor(ss, m);   // over 16 lr lanes
        float rinv = qs / sqrtf(ss * (1.f / 64.f) + 1e-6f);
        float n0v = v0 * rinv * w0, n1v = v1 * rinv * w1, n2v = v2 * rinv * w2, n3v = v3 * rinv * w3;
        float o0 = n0v * cs0 - n2v * sn0;
        float o1 = n1v * cs1 - n3v * sn1;
        float o2 = n0v * sn0 + n2v * cs0;
        float o3 = n1v * sn1 + n3v * cs1;
        int row = m0 + wr * (BM / 2) + i * 16 + quad * 4 + rg;
        int b = row >> 9, seq = row & 511;
        size_t base = ((size_t)((b * HH + h) * RR + seq)) * 64;
        dst[base + lr]      = (bf16_t)o0;
        dst[base + 16 + lr] = (bf16_t)o1;
        dst[base + 32 + lr] = (bf16_t)o2;
        dst[base + 48 + lr] = (bf16_t)o3;
      }
    }
  }
}

// =========================== the fused persistent kernel ===========================
__global__ __launch_bounds__(256, 3) void mega(
    const float* __restrict__ x,
    const float* __restrict__ Wq, const float* __restrict__ Wk,
    const float* __restrict__ Wv, const float* __restrict__ Wo,
    const float* __restrict__ qw, const float* __restrict__ kw,
    const float* __restrict__ hw,
    const float* __restrict__ lq1, const float* __restrict__ lk1,
    const float* __restrict__ lq2, const float* __restrict__ lk2,
    bf16_t* __restrict__ wbf, bf16_t* __restrict__ xd, bf16_t* __restrict__ vt,
    bf16_t* __restrict__ q1, bf16_t* __restrict__ q2,
    bf16_t* __restrict__ k1, bf16_t* __restrict__ k2,
    bf16_t* __restrict__ anorm, float* __restrict__ lowrank,
    float* __restrict__ out, unsigned* cnt) {
  __shared__ __align__(16) char smem[36864];   // gemm: sA 12288 + sB 24576 | attn: 17920
  bf16_t* sA = (bf16_t*)smem;
  bf16_t* sB = (bf16_t*)(smem + 12288);
  int t = threadIdx.x;
  int bid = blockIdx.x;
  int lane = t & 63, wv = t >> 6;
  int lr = lane & 15, quad = lane >> 4;

  // ---------------- P0: weight convert (4096 tasks) + downsample (2048 tasks) ----------
  for (int task = bid; task < 6144; task += GRID) {
    if (task < 4096) {
      int y = task >> 10;
      const float* src = (y == 0) ? Wq : (y == 1) ? Wk : (y == 2) ? Wv : Wo;
      int idx = (task & 1023) * 256 + t;
      f32x4 v = *(const f32x4*)&src[(size_t)idx * 4];
      bf16x4 o;
#pragma unroll
      for (int j = 0; j < 4; ++j) o[j] = (bf16_t)v[j];
      *(bf16x4*)&wbf[(size_t)y * 1048576 + (size_t)idx * 4] = o;
    } else {
      int idx = (task - 4096) * 256 + t;
      int c4  = idx & 255;
      int row = idx >> 8;                            // b*512 + i
      int b = row >> 9, i = row & 511;
      const float* p0 = x + (size_t)(b * LL + 8 * i + 3) * CC + c4 * 4;  // coords=8i+3.5
      f32x4 a = *(const f32x4*)p0;
      f32x4 bb = *(const f32x4*)(p0 + CC);
      bf16x4 o;
#pragma unroll
      for (int j = 0; j < 4; ++j) o[j] = (bf16_t)(0.5f * (a[j] + bb[j]));
      *(bf16x4*)&xd[(size_t)row * CC + c4 * 4] = o;
    }
  }
  gsync(cnt, GRID);

  // ---------------- P1: QKV gemm, BM=64 -> exactly 768 tiles ----------------
  {
    int z = bid >> 8, rem = bid & 255;
    int n0 = (rem & 7) * 128, m0 = (rem >> 3) * 64;
    gemm_core<0, 64, 128>(xd, wbf + (size_t)z * (1u << 20), qw, kw,
                          q1, q2, k1, k2, vt, nullptr, sA, sB, m0, n0, z, t);
  }
  gsync(cnt, 2 * GRID);

  // ---------------- P2: differential attention (1024 tasks, grid-stride) --------------
  {
    bf16_t* P   = (bf16_t*)smem;                 // [16][520]
    float* Sf   = (float*)(smem + 16640);
    float* Sm1 = Sf, *Sl1 = Sf + 64, *Sm2 = Sf + 128, *Sl2 = Sf + 192, *Sq = Sf + 256;

    float t1 = lq1[lane] * lk1[lane];
    float t2 = lq2[lane] * lk2[lane];
#pragma unroll
    for (int m = 1; m <= 32; m <<= 1) { t1 += __shfl_xor(t1, m); t2 += __shfl_xor(t2, m); }
    float lam = expf(t1) - expf(t2) + 0.8f;

    for (int task = bid; task < 1024; task += GRID) {
      int qt = task & 31, bh = task >> 5;
      int b = bh >> 3, h = bh & 7;
      const bf16_t* q1b = q1 + (size_t)(bh * RR + qt * 16) * 64;
      const bf16_t* q2b = q2 + (size_t)(bh * RR + qt * 16) * 64;
      const bf16_t* k1b = k1 + (size_t)bh * RR * 64;
      const bf16_t* k2b = k2 + (size_t)bh * RR * 64;
      const bf16_t* vtb = vt + (size_t)bh * 128 * 512;

      bf16x8 a1[2], a2[2];
#pragma unroll
      for (int kk = 0; kk < 2; ++kk) {
        a1[kk] = *(const bf16x8*)&q1b[lr * 64 + kk * 32 + quad * 8];
        a2[kk] = *(const bf16x8*)&q2b[lr * 64 + kk * 32 + quad * 8];
      }
      f32x4 s1[8], s2[8];
#pragma unroll
      for (int kt = 0; kt < 8; ++kt) {
        const bf16_t* kr = k1b + (size_t)((wv * 8 + kt) * 16 + lr) * 64 + quad * 8;
        f32x4 a = {};
        a = MFMA16(a1[0], *(const bf16x8*)kr, a);
        a = MFMA16(a1[1], *(const bf16x8*)(kr + 32), a);
        s1[kt] = a;
      }
#pragma unroll
      for (int kt = 0; kt < 8; ++kt) {
        const bf16_t* kr = k2b + (size_t)((wv * 8 + kt) * 16 + lr) * 64 + quad * 8;
        f32x4 a = {};
        a = MFMA16(a2[0], *(const bf16x8*)kr, a);
        a = MFMA16(a2[1], *(const bf16x8*)(kr + 32), a);
        s2[kt] = a;
      }
      float m1[4] = {-3e38f, -3e38f, -3e38f, -3e38f}, m2[4] = {-3e38f, -3e38f, -3e38f, -3e38f};
#pragma unroll
      for (int kt = 0; kt < 8; ++kt)
#pragma unroll
        for (int rg = 0; rg < 4; ++rg) { m1[rg] = fmaxf(m1[rg], s1[kt][rg]); m2[rg] = fmaxf(m2[rg], s2[kt][rg]); }
#pragma unroll
      for (int m = 1; m <= 8; m <<= 1)
#pragma unroll
        for (int rg = 0; rg < 4; ++rg) { m1[rg] = fmaxf(m1[rg], __shfl_xor(m1[rg], m)); m2[rg] = fmaxf(m2[rg], __shfl_xor(m2[rg], m)); }
      float l1[4] = {}, l2[4] = {};
#pragma unroll
      for (int kt = 0; kt < 8; ++kt)
#pragma unroll
        for (int rg = 0; rg < 4; ++rg) {
          float e1 = __expf(s1[kt][rg] - m1[rg]); s1[kt][rg] = e1; l1[rg] += e1;
          float e2 = __expf(s2[kt][rg] - m2[rg]); s2[kt][rg] = e2; l2[rg] += e2;
        }
#pragma unroll
      for (int m = 1; m <= 8; m <<= 1)
#pragma unroll
        for (int rg = 0; rg < 4; ++rg) { l1[rg] += __shfl_xor(l1[rg], m); l2[rg] += __shfl_xor(l2[rg], m); }
      if (lr == 0) {
#pragma unroll
        for (int rg = 0; rg < 4; ++rg) {
          int r = quad * 4 + rg;
          Sm1[wv * 16 + r] = m1[rg]; Sl1[wv * 16 + r] = l1[rg];
          Sm2[wv * 16 + r] = m2[rg]; Sl2[wv * 16 + r] = l2[rg];
        }
      }
      __syncthreads();
      float sc1[4], sc2[4];
#pragma unroll
      for (int rg = 0; rg < 4; ++rg) {
        int r = quad * 4 + rg;
        float gm1 = fmaxf(fmaxf(Sm1[r], Sm1[16 + r]), fmaxf(Sm1[32 + r], Sm1[48 + r]));
        float L1 = Sl1[r] * __expf(Sm1[r] - gm1) + Sl1[16 + r] * __expf(Sm1[16 + r] - gm1)
                 + Sl1[32 + r] * __expf(Sm1[32 + r] - gm1) + Sl1[48 + r] * __expf(Sm1[48 + r] - gm1);
        sc1[rg] = __expf(m1[rg] - gm1) / L1;
        float gm2 = fmaxf(fmaxf(Sm2[r], Sm2[16 + r]), fmaxf(Sm2[32 + r], Sm2[48 + r]));
        float L2 = Sl2[r] * __expf(Sm2[r] - gm2) + Sl2[16 + r] * __expf(Sm2[16 + r] - gm2)
                 + Sl2[32 + r] * __expf(Sm2[32 + r] - gm2) + Sl2[48 + r] * __expf(Sm2[48 + r] - gm2);
        sc2[rg] = lam * __expf(m2[rg] - gm2) / L2;
      }
#pragma unroll
      for (int kt = 0; kt < 8; ++kt)
#pragma unroll
        for (int rg = 0; rg < 4; ++rg) {
          float v = s1[kt][rg] * sc1[rg] - s2[kt][rg] * sc2[rg];
          P[(quad * 4 + rg) * 520 + (wv * 8 + kt) * 16 + lr] = (bf16_t)v;
        }
      __syncthreads();
      f32x4 accO[2] = {};
#pragma unroll
      for (int ks = 0; ks < 16; ++ks) {
        bf16x8 pf = *(bf16x8*)&P[lr * 520 + ks * 32 + quad * 8];
#pragma unroll
        for (int j = 0; j < 2; ++j) {
          int nt = wv * 2 + j;
          bf16x8 vf = *(const bf16x8*)&vtb[(size_t)(nt * 16 + lr) * 512 + ks * 32 + quad * 8];
          accO[j] = MFMA16(pf, vf, accO[j]);
        }
      }
      float ssr[4] = {};
#pragma unroll
      for (int j = 0; j < 2; ++j)
#pragma unroll
        for (int rg = 0; rg < 4; ++rg) ssr[rg] += accO[j][rg] * accO[j][rg];
#pragma unroll
      for (int m = 1; m <= 8; m <<= 1)
#pragma unroll
        for (int rg = 0; rg < 4; ++rg) ssr[rg] += __shfl_xor(ssr[rg], m);
      if (lr == 0) {
#pragma unroll
        for (int rg = 0; rg < 4; ++rg) Sq[wv * 16 + quad * 4 + rg] = ssr[rg];
      }
      __syncthreads();
#pragma unroll
      for (int j = 0; j < 2; ++j) {
        int nt = wv * 2 + j;
        float wcol = hw[nt * 16 + lr];
#pragma unroll
        for (int rg = 0; rg < 4; ++rg) {
          int r = quad * 4 + rg;
          float tot = Sq[r] + Sq[16 + r] + Sq[32 + r] + Sq[48 + r];
          float rinv = 0.2f / sqrtf(tot * (1.f / 128.f) + 1e-6f);
          int i = qt * 16 + r;
          anorm[(size_t)(b * RR + i) * 1024 + h * 128 + nt * 16 + lr] = (bf16_t)(accO[j][rg] * rinv * wcol);
        }
      }
      __syncthreads();   // protect P/S reuse across grid-stride iterations
    }
  }
  gsync(cnt, 3 * GRID);

  // ---------------- P3: output gemm + silu, BM=64 BN=64 -> 512 tiles ----------------
  if (bid < 512) {
    int n0 = (bid & 15) * 64, m0 = (bid >> 4) * 64;
    gemm_core<1, 64, 64>(anorm, wbf + (size_t)3 * (1u << 20), qw, kw,
                         nullptr, nullptr, nullptr, nullptr, nullptr, lowrank,
                         sA, sB, m0, n0, 3, t);
  }
  gsync(cnt, 4 * GRID);

  // ---------------- P4: upsample lowrank -> full output (16384 row-tasks) -------------
  for (int task = bid; task < 16384; task += GRID) {
    int j = task & 4095, b = task >> 12;
    int c = t * 4;
    float coord = 0.125f * (float)j - 0.4375f;
    coord = fminf(fmaxf(coord, 0.f), 511.f);
    int lo = (int)floorf(coord);
    int hi = lo + 1 < 511 ? lo + 1 : 511;
    float wt = coord - (float)lo;
    f32x4 a = *(const f32x4*)&lowrank[(size_t)(b * RR + lo) * CC + c];
    f32x4 bb = *(const f32x4*)&lowrank[(size_t)(b * RR + hi) * CC + c];
    f32x4 o;
#pragma unroll
    for (int q = 0; q < 4; ++q) o[q] = a[q] * (1.f - wt) + bb[q] * wt;
    *(f32x4*)&out[(size_t)(b * LL + j) * CC + c] = o;
  }
}

extern "C" void kernel_launch(void* const* d_in, const int* in_sizes, int n_in,
                              void* d_out, int out_size, void* d_ws, size_t ws_size,
                              hipStream_t stream) {
  (void)in_sizes; (void)n_in; (void)out_size; (void)ws_size;
  const float* x   = (const float*)d_in[0];
  const float* Wq  = (const float*)d_in[1];
  const float* Wk  = (const float*)d_in[2];
  const float* Wv  = (const float*)d_in[3];
  const float* Wo  = (const float*)d_in[4];
  const float* qw  = (const float*)d_in[5];
  const float* kw  = (const float*)d_in[6];
  const float* hw  = (const float*)d_in[7];
  const float* lq1 = (const float*)d_in[8];
  const float* lk1 = (const float*)d_in[9];
  const float* lq2 = (const float*)d_in[10];
  const float* lk2 = (const float*)d_in[11];
  float* out = (float*)d_out;

  char* ws = (char*)d_ws;
  bf16_t* wbf   = (bf16_t*)(ws);                    // 8 MB: Wq,Wk,Wv,Wo bf16
  bf16_t* xd    = (bf16_t*)(ws + (8u << 20));       // 4 MB
  bf16_t* vt    = (bf16_t*)(ws + (12u << 20));      // 4 MB (B,H,128,512)
  bf16_t* q1    = (bf16_t*)(ws + (16u << 20));      // 2 MB each
  bf16_t* q2    = (bf16_t*)(ws + (18u << 20));
  bf16_t* k1    = (bf16_t*)(ws + (20u << 20));
  bf16_t* k2    = (bf16_t*)(ws + (22u << 20));
  bf16_t* anorm = (bf16_t*)(ws + (24u << 20));      // 4 MB -> 28 MB
  unsigned* cnt = (unsigned*)(ws + (28u << 20));    // 8 sharded barrier counters, 128B apart

  float* lowrank = out + (size_t)NB * LL * CC;      // second output region (f32)

  hipMemsetAsync(cnt, 0, 1024, stream);             // capture-legal stream op
  mega<<<GRID, 256, 0, stream>>>(x, Wq, Wk, Wv, Wo, qw, kw, hw, lq1, lk1, lq2, lk2,
                                 wbf, xd, vt, q1, q2, k1, k2, anorm, lowrank, out, cnt);
}

// Round 4
// 232.874 us; speedup vs baseline: 2.5121x; 1.9893x over previous
//
#include <hip/hip_runtime.h>

typedef __bf16 bf16_t;
typedef __bf16 bf16x8 __attribute__((ext_vector_type(8)));
typedef __bf16 bf16x4 __attribute__((ext_vector_type(4)));
typedef float  f32x4  __attribute__((ext_vector_type(4)));

#define MFMA16(a,b,c) __builtin_amdgcn_mfma_f32_16x16x32_bf16((a),(b),(c),0,0,0)

#define NB 4          // batch
#define LL 4096       // seq
#define CC 1024       // channels
#define HH 8          // heads
#define RR 512        // low-rank seq

// ---------------- K0: fused prep: weight convert (4x 1024x1024 f32->bf16) + downsample ----
// blocks [0,4096): wcvt.  blocks [4096,6144): downsample x -> xd.
// coords = 8i+3.5 exactly -> xd[i] = 0.5*(x[8i+3]+x[8i+4])
__global__ void k_prep(const float* __restrict__ x,
                       const float* __restrict__ w0, const float* __restrict__ w1,
                       const float* __restrict__ w2, const float* __restrict__ w3,
                       bf16_t* __restrict__ wbf, bf16_t* __restrict__ xd) {
  int bid = blockIdx.x;
  if (bid < 4096) {
    int y = bid >> 10;
    const float* src = (y == 0) ? w0 : (y == 1) ? w1 : (y == 2) ? w2 : w3;
    int idx = (bid & 1023) * 256 + threadIdx.x;     // one thread = 4 elems
    f32x4 v = *(const f32x4*)&src[(size_t)idx * 4];
    bf16x4 o;
#pragma unroll
    for (int j = 0; j < 4; ++j) o[j] = (bf16_t)v[j];
    *(bf16x4*)&wbf[(size_t)y * 1048576 + (size_t)idx * 4] = o;
  } else {
    int idx = (bid - 4096) * 256 + threadIdx.x;     // one thread = 4 elems
    int c4  = idx & 255;
    int row = idx >> 8;                              // b*512 + i
    int b = row >> 9, i = row & 511;
    const float* p0 = x + (size_t)(b * LL + 8 * i + 3) * CC + c4 * 4;
    f32x4 a = *(const f32x4*)p0;
    f32x4 bb = *(const f32x4*)(p0 + CC);
    bf16x4 o;
#pragma unroll
    for (int j = 0; j < 4; ++j) o[j] = (bf16_t)(0.5f * (a[j] + bb[j]));
    *(bf16x4*)&xd[(size_t)row * CC + c4 * 4] = o;
  }
}

// ---------------- async 16B global->LDS staging (m97 pattern: unpadded stride-32 rows) ----
template <int CH>
__device__ __forceinline__ void stage_async(const bf16_t* __restrict__ g, bf16_t* __restrict__ s, int t) {
#pragma unroll
  for (int j = 0; j < CH; ++j) {
    int c = t + j * 256;                     // 16B chunk id; lane-contiguous per wave
    const bf16_t* ga = g + (c >> 2) * 1024 + (c & 3) * 8;
    bf16_t* la = s + c * 8;
    __builtin_amdgcn_global_load_lds((const __attribute__((address_space(1))) void*)ga,
                                     (__attribute__((address_space(3))) void*)la, 16, 0, 0);
  }
}

// ---------------- GEMM core: C[BM,BN] tile of A[M,1024] * W[N,1024]^T ----------------
// 3-buffer / 2-deep prefetch, counted vmcnt, one s_barrier per K-step.
// Balanced grids: gemm0 BM=64,BN=128 -> 768 blocks (3/CU); gemm1 BM=64,BN=64 -> 512 (2/CU).
// MODE 0: z=0/1 -> rmsnorm+rope -> q1/q2 | k1/k2 ; z=2 -> Vt transposed bf16
// MODE 1: Wo + silu -> f32 lowrank
template <int MODE, int BM, int BN>
__global__ __launch_bounds__(256) void k_gemm(const bf16_t* __restrict__ A,
                                              const bf16_t* __restrict__ wbf,
                                              const float* __restrict__ qw,
                                              const float* __restrict__ kw,
                                              bf16_t* __restrict__ q1, bf16_t* __restrict__ q2,
                                              bf16_t* __restrict__ k1, bf16_t* __restrict__ k2,
                                              bf16_t* __restrict__ vt, float* __restrict__ outF) {
  __shared__ bf16_t sA[3][BM * 32];
  __shared__ bf16_t sB[3][BN * 32];
  const int z = (MODE == 0) ? blockIdx.z : 3;
  const bf16_t* W = wbf + (size_t)z * (1u << 20);
  int t = threadIdx.x;
  int lane = t & 63, w = t >> 6;
  int wr = w >> 1, wc = w & 1;
  int lr = lane & 15, quad = lane >> 4;
  int m0 = blockIdx.y * BM, n0 = blockIdx.x * BN;
  constexpr int NI = BM / 32, NJ = BN / 32;
  f32x4 acc[NI][NJ] = {};
  const bf16_t* Ab = A + (size_t)m0 * 1024;
  const bf16_t* Wb = W + (size_t)n0 * 1024;

  // prologue: stage K-steps 0 and 1
  stage_async<BM / 64>(Ab, sA[0], t);
  stage_async<BN / 64>(Wb, sB[0], t);
  stage_async<BM / 64>(Ab + 32, sA[1], t);
  stage_async<BN / 64>(Wb + 32, sB[1], t);

  int cur = 0, stg = 2;
#pragma unroll 1
  for (int it = 0; it < 32; ++it) {
    if (it < 31) {
      constexpr int L = BM / 64 + BN / 64;   // loads per thread per stage
      if constexpr (L == 2) asm volatile("s_waitcnt vmcnt(2) lgkmcnt(0)" ::: "memory");
      else if constexpr (L == 3) asm volatile("s_waitcnt vmcnt(3) lgkmcnt(0)" ::: "memory");
      else asm volatile("s_waitcnt vmcnt(4) lgkmcnt(0)" ::: "memory");
    } else {
      asm volatile("s_waitcnt vmcnt(0) lgkmcnt(0)" ::: "memory");
    }
    __builtin_amdgcn_s_barrier();             // buf[it] staged everywhere; buf[it-1] reads done
    if (it < 30) {
      stage_async<BM / 64>(Ab + (it + 2) * 32, sA[stg], t);
      stage_async<BN / 64>(Wb + (it + 2) * 32, sB[stg], t);
    }
    const bf16_t* cA = sA[cur];
    const bf16_t* cB = sB[cur];
    bf16x8 af[NI], bfr[NJ];
#pragma unroll
    for (int i = 0; i < NI; ++i) af[i] = *(const bf16x8*)&cA[(wr * (BM / 2) + i * 16 + lr) * 32 + quad * 8];
#pragma unroll
    for (int j = 0; j < NJ; ++j) bfr[j] = *(const bf16x8*)&cB[(wc * (BN / 2) + j * 16 + lr) * 32 + quad * 8];
#pragma unroll
    for (int i = 0; i < NI; ++i)
#pragma unroll
      for (int j = 0; j < NJ; ++j)
        acc[i][j] = MFMA16(af[i], bfr[j], acc[i][j]);
    cur = (cur == 2) ? 0 : cur + 1;
    stg = (stg == 2) ? 0 : stg + 1;
  }

  if constexpr (MODE == 1) {
    // silu -> f32
#pragma unroll
    for (int i = 0; i < NI; ++i)
#pragma unroll
      for (int j = 0; j < NJ; ++j) {
        int row0 = m0 + wr * (BM / 2) + i * 16 + quad * 4;
        int col  = n0 + wc * (BN / 2) + j * 16 + lr;
#pragma unroll
        for (int rg = 0; rg < 4; ++rg) {
          float v = acc[i][j][rg];
          outF[(size_t)(row0 + rg) * 1024 + col] = v / (1.f + __expf(-v));
        }
      }
    return;
  } else {
    if (z == 2) {
      // Vt transposed bf16 out
#pragma unroll
      for (int i = 0; i < NI; ++i)
#pragma unroll
        for (int j = 0; j < NJ; ++j) {
          int row0 = m0 + wr * (BM / 2) + i * 16 + quad * 4;
          int col  = n0 + wc * (BN / 2) + j * 16 + lr;
          int b = row0 >> 9, ii = row0 & 511;
          int h = col >> 7, nn = col & 127;
          bf16x4 pk;
#pragma unroll
          for (int rg = 0; rg < 4; ++rg) pk[rg] = (bf16_t)acc[i][j][rg];
          *(bf16x4*)&vt[(size_t)((b * HH + h) * 128 + nn) * 512 + ii] = pk;
        }
      return;
    }
    // z<2: fused rmsnorm(64) + rope (pos = head idx) epilogue; wave col span = one (h,slot) group
    const float* nw = z ? kw : qw;
    int colbase = n0 + wc * (BN / 2);
    int h = colbase >> 7;
    int slot = (colbase >> 6) & 1;
    bf16_t* dst = (z == 0) ? (slot ? q2 : q1) : (slot ? k2 : k1);
    float qs = (z == 0) ? 0.125f : 1.0f;      // fold attn scale into q
    float w0 = nw[lr], w1 = nw[16 + lr], w2 = nw[32 + lr], w3 = nw[48 + lr];
    const float nlog = -13.287712379549449f / 32.f;   // -log2(10000)/32
    float f0 = exp2f((float)lr * nlog);
    float f1 = exp2f((float)(16 + lr) * nlog);
    float sn0, cs0, sn1, cs1;
    __sincosf((float)h * f0, &sn0, &cs0);
    __sincosf((float)h * f1, &sn1, &cs1);
#pragma unroll
    for (int i = 0; i < NI; ++i) {
#pragma unroll
      for (int rg = 0; rg < 4; ++rg) {
        float v0 = acc[i][0][rg], v1 = acc[i][1][rg], v2 = acc[i][2][rg], v3 = acc[i][3][rg];
        float ss = v0 * v0 + v1 * v1 + v2 * v2 + v3 * v3;
#pragma unroll
        for (int m = 1; m <= 8; m <<= 1) ss += __shfl_xor(ss, m);   // over 16 lr lanes
        float rinv = qs / sqrtf(ss * (1.f / 64.f) + 1e-6f);
        float n0v = v0 * rinv * w0, n1v = v1 * rinv * w1, n2v = v2 * rinv * w2, n3v = v3 * rinv * w3;
        float o0 = n0v * cs0 - n2v * sn0;
        float o1 = n1v * cs1 - n3v * sn1;
        float o2 = n0v * sn0 + n2v * cs0;
        float o3 = n1v * sn1 + n3v * cs1;
        int row = m0 + wr * (BM / 2) + i * 16 + quad * 4 + rg;
        int b = row >> 9, seq = row & 511;
        size_t base = ((size_t)((b * HH + h) * RR + seq)) * 64;
        dst[base + lr]      = (bf16_t)o0;
        dst[base + 16 + lr] = (bf16_t)o1;
        dst[base + 32 + lr] = (bf16_t)o2;
        dst[base + 48 + lr] = (bf16_t)o3;
      }
    }
  }
}

// ---------------- K4: fused differential attention, 4 waves / block ----------------
// Block handles 16 q rows of one (b,h). Wave w owns K-slice [w*128, w*128+128)
// for scores (no spills: 8 f32x4 per stream) and output cols [w*32, w*32+32) for PV.
// Cross-wave softmax via log-sum-exp merge of per-wave (m,l) stats in LDS.
__global__ __launch_bounds__(256) void k_attn(const bf16_t* __restrict__ q1, const bf16_t* __restrict__ q2,
                                              const bf16_t* __restrict__ k1, const bf16_t* __restrict__ k2,
                                              const bf16_t* __restrict__ vt,
                                              const float* __restrict__ lq1, const float* __restrict__ lk1,
                                              const float* __restrict__ lq2, const float* __restrict__ lk2,
                                              const float* __restrict__ hw, bf16_t* __restrict__ anorm) {
  __shared__ bf16_t P[16 * 520];     // combined P1 - lam*P2 (A-layout source for PV)
  __shared__ float Sm1[4][16], Sl1[4][16], Sm2[4][16], Sl2[4][16], Sq[4][16];
  int t = threadIdx.x;
  int lane = t & 63, w = t >> 6;
  int lr = lane & 15, quad = lane >> 4;
  int qt = blockIdx.x, bh = blockIdx.y;
  int b = bh >> 3, h = bh & 7;

  // lambda scalar
  float t1 = lq1[lane] * lk1[lane];
  float t2 = lq2[lane] * lk2[lane];
#pragma unroll
  for (int m = 1; m <= 32; m <<= 1) { t1 += __shfl_xor(t1, m); t2 += __shfl_xor(t2, m); }
  float lam = expf(t1) - expf(t2) + 0.8f;

  const bf16_t* q1b = q1 + (size_t)(bh * RR + qt * 16) * 64;
  const bf16_t* q2b = q2 + (size_t)(bh * RR + qt * 16) * 64;
  const bf16_t* k1b = k1 + (size_t)bh * RR * 64;
  const bf16_t* k2b = k2 + (size_t)bh * RR * 64;
  const bf16_t* vtb = vt + (size_t)bh * 128 * 512;

  bf16x8 a1[2], a2[2];
#pragma unroll
  for (int kk = 0; kk < 2; ++kk) {
    a1[kk] = *(const bf16x8*)&q1b[lr * 64 + kk * 32 + quad * 8];
    a2[kk] = *(const bf16x8*)&q2b[lr * 64 + kk * 32 + quad * 8];
  }

  // ---- scores for this wave's K-slice (8 kt tiles per stream) ----
  f32x4 s1[8], s2[8];
#pragma unroll
  for (int kt = 0; kt < 8; ++kt) {
    const bf16_t* kr = k1b + (size_t)((w * 8 + kt) * 16 + lr) * 64 + quad * 8;
    f32x4 a = {};
    a = MFMA16(a1[0], *(const bf16x8*)kr, a);
    a = MFMA16(a1[1], *(const bf16x8*)(kr + 32), a);
    s1[kt] = a;
  }
#pragma unroll
  for (int kt = 0; kt < 8; ++kt) {
    const bf16_t* kr = k2b + (size_t)((w * 8 + kt) * 16 + lr) * 64 + quad * 8;
    f32x4 a = {};
    a = MFMA16(a2[0], *(const bf16x8*)kr, a);
    a = MFMA16(a2[1], *(const bf16x8*)(kr + 32), a);
    s2[kt] = a;
  }
  // ---- per-wave softmax stats (rows live across 16 lr lanes) ----
  float m1[4] = {-3e38f, -3e38f, -3e38f, -3e38f}, m2[4] = {-3e38f, -3e38f, -3e38f, -3e38f};
#pragma unroll
  for (int kt = 0; kt < 8; ++kt)
#pragma unroll
    for (int rg = 0; rg < 4; ++rg) { m1[rg] = fmaxf(m1[rg], s1[kt][rg]); m2[rg] = fmaxf(m2[rg], s2[kt][rg]); }
#pragma unroll
  for (int m = 1; m <= 8; m <<= 1)
#pragma unroll
    for (int rg = 0; rg < 4; ++rg) { m1[rg] = fmaxf(m1[rg], __shfl_xor(m1[rg], m)); m2[rg] = fmaxf(m2[rg], __shfl_xor(m2[rg], m)); }
  float l1[4] = {}, l2[4] = {};
#pragma unroll
  for (int kt = 0; kt < 8; ++kt)
#pragma unroll
    for (int rg = 0; rg < 4; ++rg) {
      float e1 = __expf(s1[kt][rg] - m1[rg]); s1[kt][rg] = e1; l1[rg] += e1;
      float e2 = __expf(s2[kt][rg] - m2[rg]); s2[kt][rg] = e2; l2[rg] += e2;
    }
#pragma unroll
  for (int m = 1; m <= 8; m <<= 1)
#pragma unroll
    for (int rg = 0; rg < 4; ++rg) { l1[rg] += __shfl_xor(l1[rg], m); l2[rg] += __shfl_xor(l2[rg], m); }
  if (lr == 0) {
#pragma unroll
    for (int rg = 0; rg < 4; ++rg) {
      int r = quad * 4 + rg;
      Sm1[w][r] = m1[rg]; Sl1[w][r] = l1[rg];
      Sm2[w][r] = m2[rg]; Sl2[w][r] = l2[rg];
    }
  }
  __syncthreads();
  // ---- merge stats across waves, write combined P slice ----
  float sc1[4], sc2[4];
#pragma unroll
  for (int rg = 0; rg < 4; ++rg) {
    int r = quad * 4 + rg;
    float gm1 = fmaxf(fmaxf(Sm1[0][r], Sm1[1][r]), fmaxf(Sm1[2][r], Sm1[3][r]));
    float L1 = Sl1[0][r] * __expf(Sm1[0][r] - gm1) + Sl1[1][r] * __expf(Sm1[1][r] - gm1)
             + Sl1[2][r] * __expf(Sm1[2][r] - gm1) + Sl1[3][r] * __expf(Sm1[3][r] - gm1);
    sc1[rg] = __expf(m1[rg] - gm1) / L1;
    float gm2 = fmaxf(fmaxf(Sm2[0][r], Sm2[1][r]), fmaxf(Sm2[2][r], Sm2[3][r]));
    float L2 = Sl2[0][r] * __expf(Sm2[0][r] - gm2) + Sl2[1][r] * __expf(Sm2[1][r] - gm2)
             + Sl2[2][r] * __expf(Sm2[2][r] - gm2) + Sl2[3][r] * __expf(Sm2[3][r] - gm2);
    sc2[rg] = lam * __expf(m2[rg] - gm2) / L2;
  }
#pragma unroll
  for (int kt = 0; kt < 8; ++kt)
#pragma unroll
    for (int rg = 0; rg < 4; ++rg) {
      float v = s1[kt][rg] * sc1[rg] - s2[kt][rg] * sc2[rg];
      P[(quad * 4 + rg) * 520 + (w * 8 + kt) * 16 + lr] = (bf16_t)v;
    }
  __syncthreads();
  // ---- PV: this wave computes output cols [w*32, w*32+32) ----
  f32x4 accO[2] = {};
#pragma unroll
  for (int ks = 0; ks < 16; ++ks) {
    bf16x8 pf = *(bf16x8*)&P[lr * 520 + ks * 32 + quad * 8];
#pragma unroll
    for (int j = 0; j < 2; ++j) {
      int nt = w * 2 + j;
      bf16x8 vf = *(const bf16x8*)&vtb[(size_t)(nt * 16 + lr) * 512 + ks * 32 + quad * 8];
      accO[j] = MFMA16(pf, vf, accO[j]);
    }
  }
  // ---- head rmsnorm(128): partial squares per wave, LDS combine ----
  float ssr[4] = {};
#pragma unroll
  for (int j = 0; j < 2; ++j)
#pragma unroll
    for (int rg = 0; rg < 4; ++rg) ssr[rg] += accO[j][rg] * accO[j][rg];
#pragma unroll
  for (int m = 1; m <= 8; m <<= 1)
#pragma unroll
    for (int rg = 0; rg < 4; ++rg) ssr[rg] += __shfl_xor(ssr[rg], m);
  if (lr == 0) {
#pragma unroll
    for (int rg = 0; rg < 4; ++rg) Sq[w][quad * 4 + rg] = ssr[rg];
  }
  __syncthreads();
#pragma unroll
  for (int j = 0; j < 2; ++j) {
    int nt = w * 2 + j;
    float wcol = hw[nt * 16 + lr];
#pragma unroll
    for (int rg = 0; rg < 4; ++rg) {
      int r = quad * 4 + rg;
      float tot = Sq[0][r] + Sq[1][r] + Sq[2][r] + Sq[3][r];
      float rinv = 0.2f / sqrtf(tot * (1.f / 128.f) + 1e-6f);
      int i = qt * 16 + r;
      anorm[(size_t)(b * RR + i) * 1024 + h * 128 + nt * 16 + lr] = (bf16_t)(accO[j][rg] * rinv * wcol);
    }
  }
}

// ---------------- K6: upsample lowrank (B,512,1024) f32 -> full (B,4096,1024) f32 --------
__global__ void k_up(const float* __restrict__ lrk, float* __restrict__ out) {
  int j = blockIdx.x;
  int b = blockIdx.y;
  int c = threadIdx.x * 4;
  float coord = 0.125f * (float)j - 0.4375f;
  coord = fminf(fmaxf(coord, 0.f), 511.f);
  int lo = (int)floorf(coord);
  int hi = lo + 1 < 511 ? lo + 1 : 511;
  float w = coord - (float)lo;
  f32x4 a = *(const f32x4*)&lrk[(size_t)(b * RR + lo) * CC + c];
  f32x4 bb = *(const f32x4*)&lrk[(size_t)(b * RR + hi) * CC + c];
  f32x4 o;
#pragma unroll
  for (int t = 0; t < 4; ++t) o[t] = a[t] * (1.f - w) + bb[t] * w;
  *(f32x4*)&out[(size_t)(b * LL + j) * CC + c] = o;
}

extern "C" void kernel_launch(void* const* d_in, const int* in_sizes, int n_in,
                              void* d_out, int out_size, void* d_ws, size_t ws_size,
                              hipStream_t stream) {
  (void)in_sizes; (void)n_in; (void)out_size; (void)ws_size;
  const float* x   = (const float*)d_in[0];
  const float* Wq  = (const float*)d_in[1];
  const float* Wk  = (const float*)d_in[2];
  const float* Wv  = (const float*)d_in[3];
  const float* Wo  = (const float*)d_in[4];
  const float* qw  = (const float*)d_in[5];
  const float* kw  = (const float*)d_in[6];
  const float* hw  = (const float*)d_in[7];
  const float* lq1 = (const float*)d_in[8];
  const float* lk1 = (const float*)d_in[9];
  const float* lq2 = (const float*)d_in[10];
  const float* lk2 = (const float*)d_in[11];
  float* out = (float*)d_out;

  char* ws = (char*)d_ws;
  bf16_t* wbf   = (bf16_t*)(ws);                    // 8 MB: Wq,Wk,Wv,Wo bf16
  bf16_t* xd    = (bf16_t*)(ws + (8u << 20));       // 4 MB
  bf16_t* vt    = (bf16_t*)(ws + (12u << 20));      // 4 MB (B,H,128,512)
  bf16_t* q1    = (bf16_t*)(ws + (16u << 20));      // 2 MB each
  bf16_t* q2    = (bf16_t*)(ws + (18u << 20));
  bf16_t* k1    = (bf16_t*)(ws + (20u << 20));
  bf16_t* k2    = (bf16_t*)(ws + (22u << 20));
  bf16_t* anorm = (bf16_t*)(ws + (24u << 20));      // 4 MB -> 28 MB total

  float* lowrank = out + (size_t)NB * LL * CC;      // second output region (f32)

  k_prep<<<6144, 256, 0, stream>>>(x, Wq, Wk, Wv, Wo, wbf, xd);
  // balanced: 768 blocks = 3/CU
  k_gemm<0, 64, 128><<<dim3(8, 32, 3), 256, 0, stream>>>(xd, wbf, qw, kw, q1, q2, k1, k2, vt, nullptr);
  k_attn<<<dim3(32, 32), 256, 0, stream>>>(q1, q2, k1, k2, vt, lq1, lk1, lq2, lk2, hw, anorm);
  // balanced: 512 blocks = 2/CU
  k_gemm<1, 64, 64><<<dim3(16, 32, 1), 256, 0, stream>>>(anorm, wbf, qw, kw, nullptr, nullptr, nullptr, nullptr, nullptr, lowrank);
  k_up<<<dim3(4096, 4), 256, 0, stream>>>(lowrank, out);
}

// Round 5
// 221.312 us; speedup vs baseline: 2.6433x; 1.0522x over previous
//
#include <hip/hip_runtime.h>

typedef __bf16 bf16_t;
typedef __bf16 bf16x8 __attribute__((ext_vector_type(8)));
typedef __bf16 bf16x4 __attribute__((ext_vector_type(4)));
typedef float  f32x4  __attribute__((ext_vector_type(4)));

#define MFMA16(a,b,c) __builtin_amdgcn_mfma_f32_16x16x32_bf16((a),(b),(c),0,0,0)

#define NB 4          // batch
#define LL 4096       // seq
#define CC 1024       // channels
#define HH 8          // heads
#define RR 512        // low-rank seq

// ---------------- K0: fused prep: weight convert (4x 1024x1024 f32->bf16) + downsample ----
// blocks [0,4096): wcvt.  blocks [4096,6144): downsample x -> xd.
// coords = 8i+3.5 exactly -> xd[i] = 0.5*(x[8i+3]+x[8i+4])
__global__ void k_prep(const float* __restrict__ x,
                       const float* __restrict__ w0, const float* __restrict__ w1,
                       const float* __restrict__ w2, const float* __restrict__ w3,
                       bf16_t* __restrict__ wbf, bf16_t* __restrict__ xd) {
  int bid = blockIdx.x;
  if (bid < 4096) {
    int y = bid >> 10;
    const float* src = (y == 0) ? w0 : (y == 1) ? w1 : (y == 2) ? w2 : w3;
    int idx = (bid & 1023) * 256 + threadIdx.x;     // one thread = 4 elems
    f32x4 v = *(const f32x4*)&src[(size_t)idx * 4];
    bf16x4 o;
#pragma unroll
    for (int j = 0; j < 4; ++j) o[j] = (bf16_t)v[j];
    *(bf16x4*)&wbf[(size_t)y * 1048576 + (size_t)idx * 4] = o;
  } else {
    int idx = (bid - 4096) * 256 + threadIdx.x;     // one thread = 4 elems
    int c4  = idx & 255;
    int row = idx >> 8;                              // b*512 + i
    int b = row >> 9, i = row & 511;
    const float* p0 = x + (size_t)(b * LL + 8 * i + 3) * CC + c4 * 4;
    f32x4 a = *(const f32x4*)p0;
    f32x4 bb = *(const f32x4*)(p0 + CC);
    bf16x4 o;
#pragma unroll
    for (int j = 0; j < 4; ++j) o[j] = (bf16_t)(0.5f * (a[j] + bb[j]));
    *(bf16x4*)&xd[(size_t)row * CC + c4 * 4] = o;
  }
}

// ---------------- async 16B global->LDS staging (m97 pattern: unpadded stride-32 rows) ----
template <int CH>
__device__ __forceinline__ void stage_async(const bf16_t* __restrict__ g, bf16_t* __restrict__ s, int t) {
#pragma unroll
  for (int j = 0; j < CH; ++j) {
    int c = t + j * 256;                     // 16B chunk id; lane-contiguous per wave
    const bf16_t* ga = g + (c >> 2) * 1024 + (c & 3) * 8;
    bf16_t* la = s + c * 8;
    __builtin_amdgcn_global_load_lds((const __attribute__((address_space(1))) void*)ga,
                                     (__attribute__((address_space(3))) void*)la, 16, 0, 0);
  }
}

// ---------------- GEMM core: C[BM,BN] tile of A[M,1024] * W[N,1024]^T ----------------
// 3-buffer / 2-deep prefetch, counted vmcnt, one s_barrier per K-step.
// 1D grid + bijective XCD-chunked swizzle (T1): panels stay in one XCD's L2.
// MODE 0 (768 blocks, BM=64 BN=128): z=0/1 -> rmsnorm+rope -> q1/q2|k1/k2 ; z=2 -> Vt
//   (Vt store goes through an LDS transpose -> contiguous 128B global runs)
// MODE 1 (512 blocks, BM=64 BN=64): Wo + silu -> f32 lowrank
template <int MODE, int BM, int BN>
__global__ __launch_bounds__(256) void k_gemm(const bf16_t* __restrict__ A,
                                              const bf16_t* __restrict__ wbf,
                                              const float* __restrict__ qw,
                                              const float* __restrict__ kw,
                                              bf16_t* __restrict__ q1, bf16_t* __restrict__ q2,
                                              bf16_t* __restrict__ k1, bf16_t* __restrict__ k2,
                                              bf16_t* __restrict__ vt, float* __restrict__ outF) {
  __shared__ __align__(16) char smem[3 * (BM * 64) + 3 * (BN * 64)];   // bytes
  bf16_t* sA = (bf16_t*)smem;                         // 3 buffers of BM*32 elems
  bf16_t* sB = (bf16_t*)(smem + 3 * (BM * 64));       // 3 buffers of BN*32 elems

  int bid = blockIdx.x;
  int z, m0, n0;
  if constexpr (MODE == 0) {
    int task = (bid & 7) * 96 + (bid >> 3);           // 768 = 8 * 96, bijective
    z = task >> 8;
    int rem = task & 255;
    m0 = (rem >> 3) * BM; n0 = (rem & 7) * BN;        // XCD gets one z's contiguous m-panels
  } else {
    int task = (bid & 7) * 64 + (bid >> 3);           // 512 = 8 * 64, bijective
    z = 3;
    m0 = (task >> 4) * BM; n0 = (task & 15) * BN;
  }
  const bf16_t* W = wbf + (size_t)z * (1u << 20);
  int t = threadIdx.x;
  int lane = t & 63, w = t >> 6;
  int wr = w >> 1, wc = w & 1;
  int lr = lane & 15, quad = lane >> 4;
  constexpr int NI = BM / 32, NJ = BN / 32;
  f32x4 acc[NI][NJ] = {};
  const bf16_t* Ab = A + (size_t)m0 * 1024;
  const bf16_t* Wb = W + (size_t)n0 * 1024;

  // prologue: stage K-steps 0 and 1
  stage_async<BM / 64>(Ab, sA, t);
  stage_async<BN / 64>(Wb, sB, t);
  stage_async<BM / 64>(Ab + 32, sA + BM * 32, t);
  stage_async<BN / 64>(Wb + 32, sB + BN * 32, t);

  int cur = 0, stg = 2;
#pragma unroll 1
  for (int it = 0; it < 32; ++it) {
    if (it < 31) {
      constexpr int L = BM / 64 + BN / 64;   // loads per thread per stage
      if constexpr (L == 2) asm volatile("s_waitcnt vmcnt(2) lgkmcnt(0)" ::: "memory");
      else if constexpr (L == 3) asm volatile("s_waitcnt vmcnt(3) lgkmcnt(0)" ::: "memory");
      else asm volatile("s_waitcnt vmcnt(4) lgkmcnt(0)" ::: "memory");
    } else {
      asm volatile("s_waitcnt vmcnt(0) lgkmcnt(0)" ::: "memory");
    }
    __builtin_amdgcn_s_barrier();             // buf[it] staged everywhere; buf[it-1] reads done
    if (it < 30) {
      stage_async<BM / 64>(Ab + (it + 2) * 32, sA + stg * (BM * 32), t);
      stage_async<BN / 64>(Wb + (it + 2) * 32, sB + stg * (BN * 32), t);
    }
    const bf16_t* cA = sA + cur * (BM * 32);
    const bf16_t* cB = sB + cur * (BN * 32);
    bf16x8 af[NI], bfr[NJ];
#pragma unroll
    for (int i = 0; i < NI; ++i) af[i] = *(const bf16x8*)&cA[(wr * (BM / 2) + i * 16 + lr) * 32 + quad * 8];
#pragma unroll
    for (int j = 0; j < NJ; ++j) bfr[j] = *(const bf16x8*)&cB[(wc * (BN / 2) + j * 16 + lr) * 32 + quad * 8];
#pragma unroll
    for (int i = 0; i < NI; ++i)
#pragma unroll
      for (int j = 0; j < NJ; ++j)
        acc[i][j] = MFMA16(af[i], bfr[j], acc[i][j]);
    cur = (cur == 2) ? 0 : cur + 1;
    stg = (stg == 2) ? 0 : stg + 1;
  }

  if constexpr (MODE == 1) {
    // silu -> f32
#pragma unroll
    for (int i = 0; i < NI; ++i)
#pragma unroll
      for (int j = 0; j < NJ; ++j) {
        int row0 = m0 + wr * (BM / 2) + i * 16 + quad * 4;
        int col  = n0 + wc * (BN / 2) + j * 16 + lr;
#pragma unroll
        for (int rg = 0; rg < 4; ++rg) {
          float v = acc[i][j][rg];
          outF[(size_t)(row0 + rg) * 1024 + col] = v / (1.f + __expf(-v));
        }
      }
    return;
  } else {
    if (z == 2) {
      // Vt: LDS-transpose then coalesced bf16x8 stores (128B contiguous runs).
      __syncthreads();                         // all K-loop LDS reads done
      bf16_t* tp = (bf16_t*)smem;              // [128][68] bf16 = 17408 B (fits)
#pragma unroll
      for (int i = 0; i < NI; ++i)
#pragma unroll
        for (int j = 0; j < NJ; ++j) {
          int iiw = wr * (BM / 2) + i * 16 + quad * 4;   // local seq row base
          int nn  = wc * (BN / 2) + j * 16 + lr;          // output channel 0..127
          bf16x4 pk;
#pragma unroll
          for (int rg = 0; rg < 4; ++rg) pk[rg] = (bf16_t)acc[i][j][rg];
          *(bf16x4*)&tp[nn * 68 + iiw] = pk;
        }
      __syncthreads();
      int b = m0 >> 9, ii0 = m0 & 511;
      int h = n0 >> 7;                          // whole block = one head
      size_t basev = (size_t)((b * HH + h) * 128) * 512 + ii0;
#pragma unroll
      for (int r = 0; r < 4; ++r) {
        int nn = r * 32 + (t >> 3);
        int k8 = (t & 7) * 8;
        bf16x8 v = *(bf16x8*)&tp[nn * 68 + k8];
        *(bf16x8*)&vt[basev + (size_t)nn * 512 + k8] = v;
      }
      return;
    }
    // z<2: fused rmsnorm(64) + rope (pos = head idx) epilogue; wave col span = one (h,slot) group
    const float* nw = z ? kw : qw;
    int colbase = n0 + wc * (BN / 2);
    int h = colbase >> 7;
    int slot = (colbase >> 6) & 1;
    bf16_t* dst = (z == 0) ? (slot ? q2 : q1) : (slot ? k2 : k1);
    float qs = (z == 0) ? 0.125f : 1.0f;      // fold attn scale into q
    float w0 = nw[lr], w1 = nw[16 + lr], w2 = nw[32 + lr], w3 = nw[48 + lr];
    const float nlog = -13.287712379549449f / 32.f;   // -log2(10000)/32
    float f0 = exp2f((float)lr * nlog);
    float f1 = exp2f((float)(16 + lr) * nlog);
    float sn0, cs0, sn1, cs1;
    __sincosf((float)h * f0, &sn0, &cs0);
    __sincosf((float)h * f1, &sn1, &cs1);
#pragma unroll
    for (int i = 0; i < NI; ++i) {
#pragma unroll
      for (int rg = 0; rg < 4; ++rg) {
        float v0 = acc[i][0][rg], v1 = acc[i][1][rg], v2 = acc[i][2][rg], v3 = acc[i][3][rg];
        float ss = v0 * v0 + v1 * v1 + v2 * v2 + v3 * v3;
#pragma unroll
        for (int m = 1; m <= 8; m <<= 1) ss += __shfl_xor(ss, m);   // over 16 lr lanes
        float rinv = qs / sqrtf(ss * (1.f / 64.f) + 1e-6f);
        float n0v = v0 * rinv * w0, n1v = v1 * rinv * w1, n2v = v2 * rinv * w2, n3v = v3 * rinv * w3;
        float o0 = n0v * cs0 - n2v * sn0;
        float o1 = n1v * cs1 - n3v * sn1;
        float o2 = n0v * sn0 + n2v * cs0;
        float o3 = n1v * sn1 + n3v * cs1;
        int row = m0 + wr * (BM / 2) + i * 16 + quad * 4 + rg;
        int b = row >> 9, seq = row & 511;
        size_t base = ((size_t)((b * HH + h) * RR + seq)) * 64;
        dst[base + lr]      = (bf16_t)o0;
        dst[base + 16 + lr] = (bf16_t)o1;
        dst[base + 32 + lr] = (bf16_t)o2;
        dst[base + 48 + lr] = (bf16_t)o3;
      }
    }
  }
}

// ---------------- K4: fused differential attention, 4 waves / block ----------------
// 1D grid 1024, XCD-chunked: each (b,h)'s 32 q-tiles land on ONE XCD (K/V L2-resident).
// Block handles 16 q rows of one (b,h). Wave w owns K-slice [w*128, w*128+128)
// for scores and output cols [w*32, w*32+32) for PV. Cross-wave softmax via LSE merge.
__global__ __launch_bounds__(256) void k_attn(const bf16_t* __restrict__ q1, const bf16_t* __restrict__ q2,
                                              const bf16_t* __restrict__ k1, const bf16_t* __restrict__ k2,
                                              const bf16_t* __restrict__ vt,
                                              const float* __restrict__ lq1, const float* __restrict__ lk1,
                                              const float* __restrict__ lq2, const float* __restrict__ lk2,
                                              const float* __restrict__ hw, bf16_t* __restrict__ anorm) {
  __shared__ bf16_t P[16 * 520];     // combined P1 - lam*P2 (A-layout source for PV)
  __shared__ float Sm1[4][16], Sl1[4][16], Sm2[4][16], Sl2[4][16], Sq[4][16];
  int t = threadIdx.x;
  int lane = t & 63, w = t >> 6;
  int lr = lane & 15, quad = lane >> 4;
  int task = (blockIdx.x & 7) * 128 + (blockIdx.x >> 3);   // 1024 = 8*128, bijective
  int qt = task & 31, bh = task >> 5;
  int b = bh >> 3, h = bh & 7;

  // lambda scalar
  float t1 = lq1[lane] * lk1[lane];
  float t2 = lq2[lane] * lk2[lane];
#pragma unroll
  for (int m = 1; m <= 32; m <<= 1) { t1 += __shfl_xor(t1, m); t2 += __shfl_xor(t2, m); }
  float lam = expf(t1) - expf(t2) + 0.8f;

  const bf16_t* q1b = q1 + (size_t)(bh * RR + qt * 16) * 64;
  const bf16_t* q2b = q2 + (size_t)(bh * RR + qt * 16) * 64;
  const bf16_t* k1b = k1 + (size_t)bh * RR * 64;
  const bf16_t* k2b = k2 + (size_t)bh * RR * 64;
  const bf16_t* vtb = vt + (size_t)bh * 128 * 512;

  bf16x8 a1[2], a2[2];
#pragma unroll
  for (int kk = 0; kk < 2; ++kk) {
    a1[kk] = *(const bf16x8*)&q1b[lr * 64 + kk * 32 + quad * 8];
    a2[kk] = *(const bf16x8*)&q2b[lr * 64 + kk * 32 + quad * 8];
  }

  // ---- scores for this wave's K-slice (8 kt tiles per stream) ----
  f32x4 s1[8], s2[8];
#pragma unroll
  for (int kt = 0; kt < 8; ++kt) {
    const bf16_t* kr = k1b + (size_t)((w * 8 + kt) * 16 + lr) * 64 + quad * 8;
    f32x4 a = {};
    a = MFMA16(a1[0], *(const bf16x8*)kr, a);
    a = MFMA16(a1[1], *(const bf16x8*)(kr + 32), a);
    s1[kt] = a;
  }
#pragma unroll
  for (int kt = 0; kt < 8; ++kt) {
    const bf16_t* kr = k2b + (size_t)((w * 8 + kt) * 16 + lr) * 64 + quad * 8;
    f32x4 a = {};
    a = MFMA16(a2[0], *(const bf16x8*)kr, a);
    a = MFMA16(a2[1], *(const bf16x8*)(kr + 32), a);
    s2[kt] = a;
  }
  // ---- per-wave softmax stats (rows live across 16 lr lanes) ----
  float m1[4] = {-3e38f, -3e38f, -3e38f, -3e38f}, m2[4] = {-3e38f, -3e38f, -3e38f, -3e38f};
#pragma unroll
  for (int kt = 0; kt < 8; ++kt)
#pragma unroll
    for (int rg = 0; rg < 4; ++rg) { m1[rg] = fmaxf(m1[rg], s1[kt][rg]); m2[rg] = fmaxf(m2[rg], s2[kt][rg]); }
#pragma unroll
  for (int m = 1; m <= 8; m <<= 1)
#pragma unroll
    for (int rg = 0; rg < 4; ++rg) { m1[rg] = fmaxf(m1[rg], __shfl_xor(m1[rg], m)); m2[rg] = fmaxf(m2[rg], __shfl_xor(m2[rg], m)); }
  float l1[4] = {}, l2[4] = {};
#pragma unroll
  for (int kt = 0; kt < 8; ++kt)
#pragma unroll
    for (int rg = 0; rg < 4; ++rg) {
      float e1 = __expf(s1[kt][rg] - m1[rg]); s1[kt][rg] = e1; l1[rg] += e1;
      float e2 = __expf(s2[kt][rg] - m2[rg]); s2[kt][rg] = e2; l2[rg] += e2;
    }
#pragma unroll
  for (int m = 1; m <= 8; m <<= 1)
#pragma unroll
    for (int rg = 0; rg < 4; ++rg) { l1[rg] += __shfl_xor(l1[rg], m); l2[rg] += __shfl_xor(l2[rg], m); }
  if (lr == 0) {
#pragma unroll
    for (int rg = 0; rg < 4; ++rg) {
      int r = quad * 4 + rg;
      Sm1[w][r] = m1[rg]; Sl1[w][r] = l1[rg];
      Sm2[w][r] = m2[rg]; Sl2[w][r] = l2[rg];
    }
  }
  __syncthreads();
  // ---- merge stats across waves, write combined P slice ----
  float sc1[4], sc2[4];
#pragma unroll
  for (int rg = 0; rg < 4; ++rg) {
    int r = quad * 4 + rg;
    float gm1 = fmaxf(fmaxf(Sm1[0][r], Sm1[1][r]), fmaxf(Sm1[2][r], Sm1[3][r]));
    float L1 = Sl1[0][r] * __expf(Sm1[0][r] - gm1) + Sl1[1][r] * __expf(Sm1[1][r] - gm1)
             + Sl1[2][r] * __expf(Sm1[2][r] - gm1) + Sl1[3][r] * __expf(Sm1[3][r] - gm1);
    sc1[rg] = __expf(m1[rg] - gm1) / L1;
    float gm2 = fmaxf(fmaxf(Sm2[0][r], Sm2[1][r]), fmaxf(Sm2[2][r], Sm2[3][r]));
    float L2 = Sl2[0][r] * __expf(Sm2[0][r] - gm2) + Sl2[1][r] * __expf(Sm2[1][r] - gm2)
             + Sl2[2][r] * __expf(Sm2[2][r] - gm2) + Sl2[3][r] * __expf(Sm2[3][r] - gm2);
    sc2[rg] = lam * __expf(m2[rg] - gm2) / L2;
  }
#pragma unroll
  for (int kt = 0; kt < 8; ++kt)
#pragma unroll
    for (int rg = 0; rg < 4; ++rg) {
      float v = s1[kt][rg] * sc1[rg] - s2[kt][rg] * sc2[rg];
      P[(quad * 4 + rg) * 520 + (w * 8 + kt) * 16 + lr] = (bf16_t)v;
    }
  __syncthreads();
  // ---- PV: this wave computes output cols [w*32, w*32+32) ----
  f32x4 accO[2] = {};
#pragma unroll
  for (int ks = 0; ks < 16; ++ks) {
    bf16x8 pf = *(bf16x8*)&P[lr * 520 + ks * 32 + quad * 8];
#pragma unroll
    for (int j = 0; j < 2; ++j) {
      int nt = w * 2 + j;
      bf16x8 vf = *(const bf16x8*)&vtb[(size_t)(nt * 16 + lr) * 512 + ks * 32 + quad * 8];
      accO[j] = MFMA16(pf, vf, accO[j]);
    }
  }
  // ---- head rmsnorm(128): partial squares per wave, LDS combine ----
  float ssr[4] = {};
#pragma unroll
  for (int j = 0; j < 2; ++j)
#pragma unroll
    for (int rg = 0; rg < 4; ++rg) ssr[rg] += accO[j][rg] * accO[j][rg];
#pragma unroll
  for (int m = 1; m <= 8; m <<= 1)
#pragma unroll
    for (int rg = 0; rg < 4; ++rg) ssr[rg] += __shfl_xor(ssr[rg], m);
  if (lr == 0) {
#pragma unroll
    for (int rg = 0; rg < 4; ++rg) Sq[w][quad * 4 + rg] = ssr[rg];
  }
  __syncthreads();
#pragma unroll
  for (int j = 0; j < 2; ++j) {
    int nt = w * 2 + j;
    float wcol = hw[nt * 16 + lr];
#pragma unroll
    for (int rg = 0; rg < 4; ++rg) {
      int r = quad * 4 + rg;
      float tot = Sq[0][r] + Sq[1][r] + Sq[2][r] + Sq[3][r];
      float rinv = 0.2f / sqrtf(tot * (1.f / 128.f) + 1e-6f);
      int i = qt * 16 + r;
      anorm[(size_t)(b * RR + i) * 1024 + h * 128 + nt * 16 + lr] = (bf16_t)(accO[j][rg] * rinv * wcol);
    }
  }
}

// ---------------- K6: upsample lowrank (B,512,1024) f32 -> full (B,4096,1024) f32 --------
// 1D grid 16384, XCD-chunked: contiguous j ranges per XCD (lowrank rows L2-resident).
__global__ void k_up(const float* __restrict__ lrk, float* __restrict__ out) {
  int task = (blockIdx.x & 7) * 2048 + (blockIdx.x >> 3);   // 16384 = 8*2048, bijective
  int j = task & 4095;
  int b = task >> 12;
  int c = threadIdx.x * 4;
  float coord = 0.125f * (float)j - 0.4375f;
  coord = fminf(fmaxf(coord, 0.f), 511.f);
  int lo = (int)floorf(coord);
  int hi = lo + 1 < 511 ? lo + 1 : 511;
  float w = coord - (float)lo;
  f32x4 a = *(const f32x4*)&lrk[(size_t)(b * RR + lo) * CC + c];
  f32x4 bb = *(const f32x4*)&lrk[(size_t)(b * RR + hi) * CC + c];
  f32x4 o;
#pragma unroll
  for (int t = 0; t < 4; ++t) o[t] = a[t] * (1.f - w) + bb[t] * w;
  *(f32x4*)&out[(size_t)(b * LL + j) * CC + c] = o;
}

extern "C" void kernel_launch(void* const* d_in, const int* in_sizes, int n_in,
                              void* d_out, int out_size, void* d_ws, size_t ws_size,
                              hipStream_t stream) {
  (void)in_sizes; (void)n_in; (void)out_size; (void)ws_size;
  const float* x   = (const float*)d_in[0];
  const float* Wq  = (const float*)d_in[1];
  const float* Wk  = (const float*)d_in[2];
  const float* Wv  = (const float*)d_in[3];
  const float* Wo  = (const float*)d_in[4];
  const float* qw  = (const float*)d_in[5];
  const float* kw  = (const float*)d_in[6];
  const float* hw  = (const float*)d_in[7];
  const float* lq1 = (const float*)d_in[8];
  const float* lk1 = (const float*)d_in[9];
  const float* lq2 = (const float*)d_in[10];
  const float* lk2 = (const float*)d_in[11];
  float* out = (float*)d_out;

  char* ws = (char*)d_ws;
  bf16_t* wbf   = (bf16_t*)(ws);                    // 8 MB: Wq,Wk,Wv,Wo bf16
  bf16_t* xd    = (bf16_t*)(ws + (8u << 20));       // 4 MB
  bf16_t* vt    = (bf16_t*)(ws + (12u << 20));      // 4 MB (B,H,128,512)
  bf16_t* q1    = (bf16_t*)(ws + (16u << 20));      // 2 MB each
  bf16_t* q2    = (bf16_t*)(ws + (18u << 20));
  bf16_t* k1    = (bf16_t*)(ws + (20u << 20));
  bf16_t* k2    = (bf16_t*)(ws + (22u << 20));
  bf16_t* anorm = (bf16_t*)(ws + (24u << 20));      // 4 MB -> 28 MB total

  float* lowrank = out + (size_t)NB * LL * CC;      // second output region (f32)

  k_prep<<<6144, 256, 0, stream>>>(x, Wq, Wk, Wv, Wo, wbf, xd);
  k_gemm<0, 64, 128><<<768, 256, 0, stream>>>(xd, wbf, qw, kw, q1, q2, k1, k2, vt, nullptr);
  k_attn<<<1024, 256, 0, stream>>>(q1, q2, k1, k2, vt, lq1, lk1, lq2, lk2, hw, anorm);
  k_gemm<1, 64, 64><<<512, 256, 0, stream>>>(anorm, wbf, qw, kw, nullptr, nullptr, nullptr, nullptr, nullptr, lowrank);
  k_up<<<16384, 256, 0, stream>>>(lowrank, out);
}